// Round 2
// baseline (530.656 us; speedup 1.0000x reference)
//
#include <hip/hip_runtime.h>

typedef _Float16 v8h __attribute__((ext_vector_type(8)));
typedef float    v4f __attribute__((ext_vector_type(4)));

#define MFMA16(A,B,C) __builtin_amdgcn_mfma_f32_16x16x32_f16((A),(B),(C),0,0,0)

__device__ __forceinline__ float sigf(float x) {
    return __builtin_amdgcn_rcpf(1.0f + __expf(-x));
}
__device__ __forceinline__ float tanh_f(float x) {
    return fmaf(2.0f, sigf(2.0f * x), -1.0f);
}

#define RPB 16   // batch rows per block
#define TT  256  // timesteps
#define HH  64   // hidden

// 8 waves = 2/SIMD. Wave pair (jb, part): part=0 computes hHi MFMAs (+bias/x),
// part=1 computes hLo MFMAs. Partials exchanged via LDS; pointwise r-split:
// part=0 owns rows r=0,1; part=1 owns r=2,3. Numerics identical to round 1.
__global__ __launch_bounds__(512, 2)
void lstm2_kernel(const float* __restrict__ x,     // [4096][256]
                  const float* __restrict__ Wih0,  // [256][1]
                  const float* __restrict__ Whh0,  // [256][64]
                  const float* __restrict__ bih0,
                  const float* __restrict__ bhh0,
                  const float* __restrict__ Wih1,  // [256][64]
                  const float* __restrict__ Whh1,  // [256][64]
                  const float* __restrict__ bih1,
                  const float* __restrict__ bhh1,
                  const float* __restrict__ Wlin,  // [64][64]
                  const float* __restrict__ blin,
                  float* __restrict__ out)         // [4096][64]
{
    __shared__ float xl[TT][RPB];                     // 16 KB
    __shared__ __align__(16) _Float16 haHi[RPB][72];  // stride 72 f16: 16B-aligned rows
    __shared__ __align__(16) _Float16 haLo[RPB][72];
    __shared__ __align__(16) _Float16 hbHi[RPB][72];
    __shared__ __align__(16) _Float16 hbLo[RPB][72];
    __shared__ float hbF[RPB][HH];                    // final hb fp32
    __shared__ __align__(16) v4f exch[2][4][2][2][64];// [layer][jb][srcpart][rg][lane], 32 KB, addr=base+l*16: conflict-free

    const int tid   = threadIdx.x;
    const int wv    = tid >> 6;       // 0..7
    const int jb    = wv >> 1;        // column block 0..3
    const int part  = wv & 1;         // 0=hi, 1=lo
    const int l     = tid & 63;
    const int l15   = l & 15;
    const int q     = l >> 4;
    const int row0  = (int)blockIdx.x * RPB;
    const int rbase = part * 2;       // pointwise rows owned: rbase, rbase+1
    const int gbase = 2 - rbase;      // rows given to partner
    const int jj    = jb * 16 + l15;

    // ---- preload x transposed; zero h state ----
    for (int idx = tid; idx < RPB * TT; idx += 512) {
        int m = idx >> 8, t = idx & (TT - 1);
        xl[t][m] = x[(row0 + m) * TT + t];
    }
    for (int idx = tid; idx < RPB * 72; idx += 512) {
        int m = idx / 72, k = idx % 72;
        haHi[m][k] = (_Float16)0.f; haLo[m][k] = (_Float16)0.f;
        hbHi[m][k] = (_Float16)0.f; hbLo[m][k] = (_Float16)0.f;
    }

    // ---- register-stationary weights (per jb; both waves of pair hold same) ----
    float wi0[4], b0c[4], b1c[4];
    v8h wh0[4][2], wi1[4][2], wh1[4][2];
    #pragma unroll
    for (int tau = 0; tau < 4; tau++) {
        int n = tau * 64 + jb * 16 + l15;
        wi0[tau] = Wih0[n];
        b0c[tau] = bih0[n] + bhh0[n];
        b1c[tau] = bih1[n] + bhh1[n];
        #pragma unroll
        for (int kk = 0; kk < 2; kk++) {
            int k0 = kk * 32 + q * 8;     // B-frag: B[k0..k0+7][n=lane&15]
            v8h a, b, c;
            #pragma unroll
            for (int j = 0; j < 8; j++) {
                a[j] = (_Float16)Whh0[n * HH + k0 + j];
                b[j] = (_Float16)Wih1[n * HH + k0 + j];
                c[j] = (_Float16)Whh1[n * HH + k0 + j];
            }
            wh0[tau][kk] = a; wi1[tau][kk] = b; wh1[tau][kk] = c;
        }
    }

    float ca[2] = {0.f, 0.f};   // c-state for rows m = q*4 + rbase + s
    float cb[2] = {0.f, 0.f};

    __syncthreads();

    for (int t = 0; t < TT; t++) {
        v4f xv = *(const v4f*)&xl[t][q * 4];

        // ============ layer 0 partial: own half of h ============
        v4f acc[4];
        if (part == 0) {
            #pragma unroll
            for (int tau = 0; tau < 4; tau++)
                #pragma unroll
                for (int r = 0; r < 4; r++) acc[tau][r] = fmaf(xv[r], wi0[tau], b0c[tau]);
        } else {
            #pragma unroll
            for (int tau = 0; tau < 4; tau++) acc[tau] = (v4f){0.f, 0.f, 0.f, 0.f};
        }
        {
            const _Float16 (*hap)[72] = part ? haLo : haHi;
            v8h a0 = *(const v8h*)&hap[l15][q * 8];
            v8h a1 = *(const v8h*)&hap[l15][32 + q * 8];
            #pragma unroll
            for (int tau = 0; tau < 4; tau++) {
                acc[tau] = MFMA16(a0, wh0[tau][0], acc[tau]);
                acc[tau] = MFMA16(a1, wh0[tau][1], acc[tau]);
            }
        }
        // give partner its rows' partials (includes bias+x if part==0)
        {
            v4f p0 = {acc[0][gbase], acc[1][gbase], acc[2][gbase], acc[3][gbase]};
            v4f p1 = {acc[0][gbase+1], acc[1][gbase+1], acc[2][gbase+1], acc[3][gbase+1]};
            exch[0][jb][part][0][l] = p0;
            exch[0][jb][part][1][l] = p1;
        }
        __syncthreads();   // B1: GEMM0 h-reads done; partials visible
        {
            v4f r0 = exch[0][jb][1 - part][0][l];
            v4f r1 = exch[0][jb][1 - part][1][l];
            float haNew[2];
            #pragma unroll
            for (int s = 0; s < 2; s++) {
                v4f rr = s ? r1 : r0;
                float gi = acc[0][rbase + s] + rr[0];
                float gf = acc[1][rbase + s] + rr[1];
                float gg = acc[2][rbase + s] + rr[2];
                float go = acc[3][rbase + s] + rr[3];
                float iv = sigf(gi), fv = sigf(gf);
                float gv = tanh_f(gg), ov = sigf(go);
                ca[s] = fmaf(fv, ca[s], iv * gv);
                haNew[s] = ov * tanh_f(ca[s]);
            }
            #pragma unroll
            for (int s = 0; s < 2; s++) {
                int m = q * 4 + rbase + s;
                _Float16 hi = (_Float16)haNew[s];
                haHi[m][jj] = hi;
                haLo[m][jj] = (_Float16)(haNew[s] - (float)hi);
            }
        }
        __syncthreads();   // B2: new ha visible

        // ============ layer 1 partial: own half of ha_new and hb ============
        if (part == 0) {
            #pragma unroll
            for (int tau = 0; tau < 4; tau++)
                acc[tau] = (v4f){b1c[tau], b1c[tau], b1c[tau], b1c[tau]};
        } else {
            #pragma unroll
            for (int tau = 0; tau < 4; tau++) acc[tau] = (v4f){0.f, 0.f, 0.f, 0.f};
        }
        {
            const _Float16 (*hap)[72] = part ? haLo : haHi;
            const _Float16 (*hbp)[72] = part ? hbLo : hbHi;
            v8h a0 = *(const v8h*)&hap[l15][q * 8];
            v8h a1 = *(const v8h*)&hap[l15][32 + q * 8];
            v8h b0 = *(const v8h*)&hbp[l15][q * 8];
            v8h b1 = *(const v8h*)&hbp[l15][32 + q * 8];
            #pragma unroll
            for (int tau = 0; tau < 4; tau++) {
                acc[tau] = MFMA16(a0, wi1[tau][0], acc[tau]);
                acc[tau] = MFMA16(a1, wi1[tau][1], acc[tau]);
                acc[tau] = MFMA16(b0, wh1[tau][0], acc[tau]);
                acc[tau] = MFMA16(b1, wh1[tau][1], acc[tau]);
            }
        }
        {
            v4f p0 = {acc[0][gbase], acc[1][gbase], acc[2][gbase], acc[3][gbase]};
            v4f p1 = {acc[0][gbase+1], acc[1][gbase+1], acc[2][gbase+1], acc[3][gbase+1]};
            exch[1][jb][part][0][l] = p0;
            exch[1][jb][part][1][l] = p1;
        }
        __syncthreads();   // B3: GEMM1 h-reads done; partials visible
        {
            v4f r0 = exch[1][jb][1 - part][0][l];
            v4f r1 = exch[1][jb][1 - part][1][l];
            float hbNew[2];
            #pragma unroll
            for (int s = 0; s < 2; s++) {
                v4f rr = s ? r1 : r0;
                float gi = acc[0][rbase + s] + rr[0];
                float gf = acc[1][rbase + s] + rr[1];
                float gg = acc[2][rbase + s] + rr[2];
                float go = acc[3][rbase + s] + rr[3];
                float iv = sigf(gi), fv = sigf(gf);
                float gv = tanh_f(gg), ov = sigf(go);
                cb[s] = fmaf(fv, cb[s], iv * gv);
                hbNew[s] = ov * tanh_f(cb[s]);
            }
            #pragma unroll
            for (int s = 0; s < 2; s++) {
                int m = q * 4 + rbase + s;
                _Float16 hi = (_Float16)hbNew[s];
                hbHi[m][jj] = hi;
                hbLo[m][jj] = (_Float16)(hbNew[s] - (float)hi);
                if (t == TT - 1) hbF[m][jj] = hbNew[s];
            }
        }
        // no 4th barrier: hb writes (post-B3) are read only after next B2;
        // exch[0] writes next step (pre-next-B1) vs this step's exch[0] reads
        // (pre-B2) are barrier-ordered. All pairs checked.
    }
    __syncthreads();

    // ---- out[m][n] = hbF[m][:] . Wlin[n][:] + blin[n], 512 threads ----
    int m  = tid >> 5;
    int n0 = (tid & 31) * 2;
    float a0o = blin[n0], a1o = blin[n0 + 1];
    #pragma unroll 8
    for (int j = 0; j < HH; j++) {
        float h = hbF[m][j];
        a0o = fmaf(h, Wlin[(n0 + 0) * HH + j], a0o);
        a1o = fmaf(h, Wlin[(n0 + 1) * HH + j], a1o);
    }
    out[(row0 + m) * HH + n0]     = a0o;
    out[(row0 + m) * HH + n0 + 1] = a1o;
}

extern "C" void kernel_launch(void* const* d_in, const int* in_sizes, int n_in,
                              void* d_out, int out_size, void* d_ws, size_t ws_size,
                              hipStream_t stream) {
    const float* x    = (const float*)d_in[0];
    const float* Wih0 = (const float*)d_in[1];
    const float* Whh0 = (const float*)d_in[2];
    const float* bih0 = (const float*)d_in[3];
    const float* bhh0 = (const float*)d_in[4];
    const float* Wih1 = (const float*)d_in[5];
    const float* Whh1 = (const float*)d_in[6];
    const float* bih1 = (const float*)d_in[7];
    const float* bhh1 = (const float*)d_in[8];
    const float* Wlin = (const float*)d_in[9];
    const float* blin = (const float*)d_in[10];
    lstm2_kernel<<<256, 512, 0, stream>>>(x, Wih0, Whh0, bih0, bhh0,
                                          Wih1, Whh1, bih1, bhh1,
                                          Wlin, blin, (float*)d_out);
}

// Round 3
// 450.792 us; speedup vs baseline: 1.1772x; 1.1772x over previous
//
#include <hip/hip_runtime.h>

typedef _Float16 v8h __attribute__((ext_vector_type(8)));
typedef float    v4f __attribute__((ext_vector_type(4)));

#define MFMA16(A,B,C) __builtin_amdgcn_mfma_f32_16x16x32_f16((A),(B),(C),0,0,0)

// Gate pre-activations arrive pre-scaled (scale folded into W/b):
//   sigmoid gates (i,f,o): y = -log2(e) * z  ->  sigma(z) = rcp(1 + 2^y)
//   tanh gate (g):         y = 2*log2(e) * z ->  tanh(z)  = 1 - 2*rcp(1 + 2^y)
__device__ __forceinline__ float sigc(float y) {
    return __builtin_amdgcn_rcpf(1.0f + __builtin_exp2f(y));
}
__device__ __forceinline__ float tanhc(float y) {
    return fmaf(-2.0f, __builtin_amdgcn_rcpf(1.0f + __builtin_exp2f(y)), 1.0f);
}

#define RPB 16   // batch rows per block
#define TT  256  // timesteps
#define HH  64   // hidden
#define L2E 1.44269504f
#define TSC 2.88539008f   // 2*log2(e)

// 4 waves / 256 threads / 1 block per CU (round-1 structure).
// Layer-merged pipeline: iteration k computes GEMM0(k) [-> ha(k)] and
// GEMM1(k-1) [-> hb(k-1)] off the SAME ha(k-1) A-fragments, one barrier/step.
__global__ __launch_bounds__(256, 1)
void lstm2_kernel(const float* __restrict__ x,     // [4096][256]
                  const float* __restrict__ Wih0,  // [256][1]
                  const float* __restrict__ Whh0,  // [256][64]
                  const float* __restrict__ bih0,
                  const float* __restrict__ bhh0,
                  const float* __restrict__ Wih1,  // [256][64]
                  const float* __restrict__ Whh1,  // [256][64]
                  const float* __restrict__ bih1,
                  const float* __restrict__ bhh1,
                  const float* __restrict__ Wlin,  // [64][64]
                  const float* __restrict__ blin,
                  float* __restrict__ out)         // [4096][64]
{
    __shared__ float xl[TT][RPB];                      // 16 KB, x transposed
    // hs[parity][0=haHi,1=haLo,2=hbHi,3=hbLo][m][col], stride 72 f16 = 144 B (16B-aligned rows)
    __shared__ __align__(16) _Float16 hs[2][4][RPB][72];   // 18 KB
    __shared__ float hbF[RPB][HH];                     // 4 KB, final hb fp32

    const int tid  = threadIdx.x;
    const int w    = tid >> 6;      // wave 0..3 -> column block
    const int l    = tid & 63;
    const int l15  = l & 15;
    const int q    = l >> 4;
    const int row0 = (int)blockIdx.x * RPB;
    const int jj   = w * 16 + l15;

    for (int idx = tid; idx < RPB * TT; idx += 256) {
        int m = idx >> 8, t = idx & (TT - 1);
        xl[t][m] = x[(row0 + m) * TT + t];
    }
    for (int idx = tid; idx < 2 * 4 * RPB * 72; idx += 256)
        ((_Float16*)hs)[idx] = (_Float16)0.f;

    // ---- register-stationary, pre-scaled weights ----
    float wi0s[4], b0s[4], b1s[4];
    v8h wh0[4][2], wi1[4][2], wh1[4][2];
    #pragma unroll
    for (int tau = 0; tau < 4; tau++) {
        float sc = (tau == 2) ? TSC : -L2E;
        int n = tau * 64 + jj;
        wi0s[tau] = Wih0[n] * sc;
        b0s[tau]  = (bih0[n] + bhh0[n]) * sc;
        b1s[tau]  = (bih1[n] + bhh1[n]) * sc;
        #pragma unroll
        for (int kk = 0; kk < 2; kk++) {
            int k0 = kk * 32 + q * 8;     // B-frag: B[k0..k0+7][n=lane&15]
            v8h a, b, c;
            #pragma unroll
            for (int j = 0; j < 8; j++) {
                a[j] = (_Float16)(Whh0[n * HH + k0 + j] * sc);
                b[j] = (_Float16)(Wih1[n * HH + k0 + j] * sc);
                c[j] = (_Float16)(Whh1[n * HH + k0 + j] * sc);
            }
            wh0[tau][kk] = a; wi1[tau][kk] = b; wh1[tau][kk] = c;
        }
    }

    float ca[4] = {0.f, 0.f, 0.f, 0.f};
    float cb[4] = {0.f, 0.f, 0.f, 0.f};
    __syncthreads();

    // ---- prologue k=0: ha(0) from x(0) only (ha(-1)=0, no MFMA) ----
    {
        v4f xv = *(const v4f*)&xl[0][q * 4];
        #pragma unroll
        for (int r = 0; r < 4; r++) {
            float gi = fmaf(xv[r], wi0s[0], b0s[0]);
            float gf = fmaf(xv[r], wi0s[1], b0s[1]);
            float gg = fmaf(xv[r], wi0s[2], b0s[2]);
            float go = fmaf(xv[r], wi0s[3], b0s[3]);
            float iv = sigc(gi), fv = sigc(gf), gv = tanhc(gg), ov = sigc(go);
            ca[r] = iv * gv;
            float hv = ov * tanhc(ca[r] * TSC);
            int m = q * 4 + r;
            _Float16 hi = (_Float16)hv;
            hs[0][0][m][jj] = hi;
            hs[0][1][m][jj] = (_Float16)(hv - (float)hi);
        }
        __syncthreads();
    }

    // ---- merged step: read buf[p] {ha(k-1),hb(k-2)}; write buf[1-p] {ha(k),hb(k-1)} ----
    auto step = [&](int k, int p) {
        v8h aHi0 = *(const v8h*)&hs[p][0][l15][q * 8];
        v8h aHi1 = *(const v8h*)&hs[p][0][l15][32 + q * 8];
        v8h aLo0 = *(const v8h*)&hs[p][1][l15][q * 8];
        v8h aLo1 = *(const v8h*)&hs[p][1][l15][32 + q * 8];
        v8h bHi0 = *(const v8h*)&hs[p][2][l15][q * 8];
        v8h bHi1 = *(const v8h*)&hs[p][2][l15][32 + q * 8];
        v8h bLo0 = *(const v8h*)&hs[p][3][l15][q * 8];
        v8h bLo1 = *(const v8h*)&hs[p][3][l15][32 + q * 8];
        v4f xv   = *(const v4f*)&xl[k][q * 4];

        v4f acc0[4], acc1[4];
        #pragma unroll
        for (int tau = 0; tau < 4; tau++) {
            #pragma unroll
            for (int r = 0; r < 4; r++) acc0[tau][r] = fmaf(xv[r], wi0s[tau], b0s[tau]);
            acc1[tau] = (v4f){b1s[tau], b1s[tau], b1s[tau], b1s[tau]};
        }
        #pragma unroll
        for (int tau = 0; tau < 4; tau++) {
            acc0[tau] = MFMA16(aHi0, wh0[tau][0], acc0[tau]);
            acc0[tau] = MFMA16(aHi1, wh0[tau][1], acc0[tau]);
            acc0[tau] = MFMA16(aLo0, wh0[tau][0], acc0[tau]);
            acc0[tau] = MFMA16(aLo1, wh0[tau][1], acc0[tau]);
            acc1[tau] = MFMA16(aHi0, wi1[tau][0], acc1[tau]);
            acc1[tau] = MFMA16(aHi1, wi1[tau][1], acc1[tau]);
            acc1[tau] = MFMA16(aLo0, wi1[tau][0], acc1[tau]);
            acc1[tau] = MFMA16(aLo1, wi1[tau][1], acc1[tau]);
            acc1[tau] = MFMA16(bHi0, wh1[tau][0], acc1[tau]);
            acc1[tau] = MFMA16(bHi1, wh1[tau][1], acc1[tau]);
            acc1[tau] = MFMA16(bLo0, wh1[tau][0], acc1[tau]);
            acc1[tau] = MFMA16(bLo1, wh1[tau][1], acc1[tau]);
        }
        const int pw = 1 - p;
        #pragma unroll
        for (int r = 0; r < 4; r++) {
            int m = q * 4 + r;
            {   // layer 0 -> ha(k)
                float iv = sigc(acc0[0][r]), fv = sigc(acc0[1][r]);
                float gv = tanhc(acc0[2][r]), ov = sigc(acc0[3][r]);
                ca[r] = fmaf(fv, ca[r], iv * gv);
                float hv = ov * tanhc(ca[r] * TSC);
                _Float16 hi = (_Float16)hv;
                hs[pw][0][m][jj] = hi;
                hs[pw][1][m][jj] = (_Float16)(hv - (float)hi);
            }
            {   // layer 1 -> hb(k-1)
                float iv = sigc(acc1[0][r]), fv = sigc(acc1[1][r]);
                float gv = tanhc(acc1[2][r]), ov = sigc(acc1[3][r]);
                cb[r] = fmaf(fv, cb[r], iv * gv);
                float hv = ov * tanhc(cb[r] * TSC);
                _Float16 hi = (_Float16)hv;
                hs[pw][2][m][jj] = hi;
                hs[pw][3][m][jj] = (_Float16)(hv - (float)hi);
            }
        }
        __syncthreads();
    };

    // k = 1..255; parity p=(k-1)&1. 2x-unrolled so LDS offsets are immediates.
    for (int k = 1; k < TT - 1; k += 2) { step(k, 0); step(k + 1, 1); }
    step(TT - 1, 0);

    // ---- epilogue: hb(255) from ha(255), hb(254) in buf[1] ----
    {
        v8h aHi0 = *(const v8h*)&hs[1][0][l15][q * 8];
        v8h aHi1 = *(const v8h*)&hs[1][0][l15][32 + q * 8];
        v8h aLo0 = *(const v8h*)&hs[1][1][l15][q * 8];
        v8h aLo1 = *(const v8h*)&hs[1][1][l15][32 + q * 8];
        v8h bHi0 = *(const v8h*)&hs[1][2][l15][q * 8];
        v8h bHi1 = *(const v8h*)&hs[1][2][l15][32 + q * 8];
        v8h bLo0 = *(const v8h*)&hs[1][3][l15][q * 8];
        v8h bLo1 = *(const v8h*)&hs[1][3][l15][32 + q * 8];
        v4f acc1[4];
        #pragma unroll
        for (int tau = 0; tau < 4; tau++)
            acc1[tau] = (v4f){b1s[tau], b1s[tau], b1s[tau], b1s[tau]};
        #pragma unroll
        for (int tau = 0; tau < 4; tau++) {
            acc1[tau] = MFMA16(aHi0, wi1[tau][0], acc1[tau]);
            acc1[tau] = MFMA16(aHi1, wi1[tau][1], acc1[tau]);
            acc1[tau] = MFMA16(aLo0, wi1[tau][0], acc1[tau]);
            acc1[tau] = MFMA16(aLo1, wi1[tau][1], acc1[tau]);
            acc1[tau] = MFMA16(bHi0, wh1[tau][0], acc1[tau]);
            acc1[tau] = MFMA16(bHi1, wh1[tau][1], acc1[tau]);
            acc1[tau] = MFMA16(bLo0, wh1[tau][0], acc1[tau]);
            acc1[tau] = MFMA16(bLo1, wh1[tau][1], acc1[tau]);
        }
        #pragma unroll
        for (int r = 0; r < 4; r++) {
            float iv = sigc(acc1[0][r]), fv = sigc(acc1[1][r]);
            float gv = tanhc(acc1[2][r]), ov = sigc(acc1[3][r]);
            cb[r] = fmaf(fv, cb[r], iv * gv);
            hbF[q * 4 + r][jj] = ov * tanhc(cb[r] * TSC);
        }
        __syncthreads();
    }

    // ---- out[m][n] = hbF[m][:] . Wlin[n][:] + blin[n] ----
    int m  = tid >> 4;
    int n0 = (tid & 15) * 4;
    float accO[4] = {blin[n0], blin[n0 + 1], blin[n0 + 2], blin[n0 + 3]};
    #pragma unroll 8
    for (int j = 0; j < HH; j++) {
        float h = hbF[m][j];
        #pragma unroll
        for (int d = 0; d < 4; d++)
            accO[d] = fmaf(h, Wlin[(n0 + d) * HH + j], accO[d]);
    }
    v4f ov = {accO[0], accO[1], accO[2], accO[3]};
    *(v4f*)&out[(row0 + m) * HH + n0] = ov;
}

extern "C" void kernel_launch(void* const* d_in, const int* in_sizes, int n_in,
                              void* d_out, int out_size, void* d_ws, size_t ws_size,
                              hipStream_t stream) {
    const float* x    = (const float*)d_in[0];
    const float* Wih0 = (const float*)d_in[1];
    const float* Whh0 = (const float*)d_in[2];
    const float* bih0 = (const float*)d_in[3];
    const float* bhh0 = (const float*)d_in[4];
    const float* Wih1 = (const float*)d_in[5];
    const float* Whh1 = (const float*)d_in[6];
    const float* bih1 = (const float*)d_in[7];
    const float* bhh1 = (const float*)d_in[8];
    const float* Wlin = (const float*)d_in[9];
    const float* blin = (const float*)d_in[10];
    lstm2_kernel<<<256, 256, 0, stream>>>(x, Wih0, Whh0, bih0, bhh0,
                                          Wih1, Whh1, bih1, bhh1,
                                          Wlin, blin, (float*)d_out);
}

// Round 4
// 412.248 us; speedup vs baseline: 1.2872x; 1.0935x over previous
//
#include <hip/hip_runtime.h>

typedef _Float16 v8h __attribute__((ext_vector_type(8)));
typedef float    v4f __attribute__((ext_vector_type(4)));

#define MFMA16(A,B,C) __builtin_amdgcn_mfma_f32_16x16x32_f16((A),(B),(C),0,0,0)

// Pre-scaled gates (scale folded into W/b):
//   sigmoid gates: y = -log2(e)*z -> sigma = rcp(1 + 2^y)
//   tanh gate:     y = 2*log2(e)*z -> tanh  = 1 - 2*rcp(1 + 2^y)
__device__ __forceinline__ float sigc(float y) {
    return __builtin_amdgcn_rcpf(1.0f + __builtin_exp2f(y));
}
__device__ __forceinline__ float tanhc(float y) {
    return fmaf(-2.0f, __builtin_amdgcn_rcpf(1.0f + __builtin_exp2f(y)), 1.0f);
}

#define RPB 8    // batch rows per block
#define TT  256
#define HH  64
#define L2E 1.44269504f
#define TSC 2.88539008f  // 2*log2(e)

// 512 blocks x 256 threads = 2 independent blocks/CU (independent barriers ->
// cross-block stall hiding; R2 showed same-block waves lockstep).
// M-dim dual-use: A-tile rows 0-7 = ha (layer0 GEMM -> C rows 0-7, lanes q<2),
// rows 8-15 = ha dup (layer1 cross GEMM -> C rows 8-15, lanes q>=2); hb lives
// only in rows 8-15 of its tile (rows 0-7 stay zero). One pointwise instance
// set (4/lane) covers BOTH layers branchlessly via gate selects.
// h stored single-f16 (no hi/lo compensation): halves MFMA count.
__global__ __launch_bounds__(256, 2)
void lstm2_kernel(const float* __restrict__ x,     // [4096][256]
                  const float* __restrict__ Wih0,  // [256][1]
                  const float* __restrict__ Whh0,  // [256][64]
                  const float* __restrict__ bih0,
                  const float* __restrict__ bhh0,
                  const float* __restrict__ Wih1,  // [256][64]
                  const float* __restrict__ Whh1,  // [256][64]
                  const float* __restrict__ bih1,
                  const float* __restrict__ bhh1,
                  const float* __restrict__ Wlin,  // [64][64]
                  const float* __restrict__ blin,
                  float* __restrict__ out)         // [4096][64]
{
    __shared__ float xl[TT][RPB];                      // 8 KB, x transposed
    __shared__ __align__(16) _Float16 hsA[2][16][72];  // ha tiles (rows 0-7 + dup 8-15), stride 72 f16
    __shared__ __align__(16) _Float16 hsB[2][16][72];  // hb tiles (rows 8-15; 0-7 stay zero)
    __shared__ float hbF[RPB][HH];                     // final hb fp32

    const int tid  = threadIdx.x;
    const int w    = tid >> 6;      // wave 0..3 -> column block
    const int l    = tid & 63;
    const int l15  = l & 15;
    const int q    = l >> 4;
    const int row0 = (int)blockIdx.x * RPB;
    const int jj   = w * 16 + l15;
    const bool isA = (q < 2);       // q<2: layer-0 lanes; q>=2: layer-1 lanes

    for (int idx = tid; idx < RPB * TT; idx += 256) {
        int m = idx >> 8, t = idx & (TT - 1);
        xl[t][m] = x[(row0 + m) * TT + t];
    }
    for (int idx = tid; idx < 2 * 16 * 72; idx += 256) {
        ((_Float16*)hsA)[idx] = (_Float16)0.f;
        ((_Float16*)hsB)[idx] = (_Float16)0.f;
    }

    // ---- register-stationary, pre-scaled f16 weights ----
    float wi0s[4], b0s[4], b1s[4];
    v8h wh0[4][2], wi1[4][2], wh1[4][2];
    #pragma unroll
    for (int tau = 0; tau < 4; tau++) {
        float sc = (tau == 2) ? TSC : -L2E;
        int n = tau * 64 + jj;
        wi0s[tau] = Wih0[n] * sc;
        b0s[tau]  = (bih0[n] + bhh0[n]) * sc;
        b1s[tau]  = (bih1[n] + bhh1[n]) * sc;
        #pragma unroll
        for (int kk = 0; kk < 2; kk++) {
            int k0 = kk * 32 + q * 8;     // B-frag: B[k0..k0+7][n=lane&15]
            v8h a, b, c;
            #pragma unroll
            for (int j = 0; j < 8; j++) {
                a[j] = (_Float16)(Whh0[n * HH + k0 + j] * sc);
                b[j] = (_Float16)(Wih1[n * HH + k0 + j] * sc);
                c[j] = (_Float16)(Whh1[n * HH + k0 + j] * sc);
            }
            wh0[tau][kk] = a; wi1[tau][kk] = b; wh1[tau][kk] = c;
        }
    }

    float cs[4] = {0.f, 0.f, 0.f, 0.f};  // per-lane c-state: 4 rows of OWN layer
    __syncthreads();

    // ---- prologue t=0: ha(0) from x(0) only (layer-0 lanes) ----
    if (isA) {
        v4f xv = *(const v4f*)&xl[0][(q & 1) * 4];
        #pragma unroll
        for (int r = 0; r < 4; r++) {
            float gi = fmaf(xv[r], wi0s[0], b0s[0]);
            float gf = fmaf(xv[r], wi0s[1], b0s[1]);
            float gg = fmaf(xv[r], wi0s[2], b0s[2]);
            float go = fmaf(xv[r], wi0s[3], b0s[3]);
            float iv = sigc(gi), fv = sigc(gf), gv = tanhc(gg), ov = sigc(go);
            (void)fv;
            cs[r] = iv * gv;
            float hv = ov * tanhc(cs[r] * TSC);
            _Float16 hh = (_Float16)hv;
            hsA[0][q * 4 + r][jj]     = hh;
            hsA[0][q * 4 + r + 8][jj] = hh;
        }
    }
    __syncthreads();

    // step k (1..256): reads buf[p] {ha(k-1), hb(k-2)}, writes buf[pw] {ha(k), hb(k-1)}
    auto step = [&](int k, int p, int pw, bool last) {
        v8h a0 = *(const v8h*)&hsA[p][l15][q * 8];
        v8h a1 = *(const v8h*)&hsA[p][l15][32 + q * 8];
        v8h b0 = *(const v8h*)&hsB[p][l15][q * 8];
        v8h b1 = *(const v8h*)&hsB[p][l15][32 + q * 8];
        int kx = (k < TT) ? k : (TT - 1);             // k=256 reads junk x, unused
        v4f xv = *(const v4f*)&xl[kx][(q & 1) * 4];

        v4f acc0[4], acc1[4];
        #pragma unroll
        for (int tau = 0; tau < 4; tau++) {
            #pragma unroll
            for (int r = 0; r < 4; r++) acc0[tau][r] = fmaf(xv[r], wi0s[tau], b0s[tau]);
            acc1[tau] = (v4f){b1s[tau], b1s[tau], b1s[tau], b1s[tau]};
        }
        #pragma unroll
        for (int tau = 0; tau < 4; tau++) {
            acc0[tau] = MFMA16(a0, wh0[tau][0], acc0[tau]);   // layer0: C rows 0-7
            acc0[tau] = MFMA16(a1, wh0[tau][1], acc0[tau]);
            acc1[tau] = MFMA16(a0, wi1[tau][0], acc1[tau]);   // layer1 cross: rows 8-15 (ha dup)
            acc1[tau] = MFMA16(a1, wi1[tau][1], acc1[tau]);
            acc1[tau] = MFMA16(b0, wh1[tau][0], acc1[tau]);   // layer1 recurrent: rows 8-15
            acc1[tau] = MFMA16(b1, wh1[tau][1], acc1[tau]);
        }

        // branchless gate select: q<2 -> layer0 accs, q>=2 -> layer1 accs
        v4f g0 = isA ? acc0[0] : acc1[0];
        v4f g1 = isA ? acc0[1] : acc1[1];
        v4f g2 = isA ? acc0[2] : acc1[2];
        v4f g3 = isA ? acc0[3] : acc1[3];

        _Float16* base = isA ? &hsA[pw][0][0] : &hsB[pw][0][0];
        _Float16* wp   = base + (q * 4) * 72 + jj;    // rows q*4+r (q>=2 -> rows 8-15)

        #pragma unroll
        for (int r = 0; r < 4; r++) {
            float iv = sigc(g0[r]), fv = sigc(g1[r]);
            float gv = tanhc(g2[r]), ov = sigc(g3[r]);
            cs[r] = fmaf(fv, cs[r], iv * gv);
            float hv = ov * tanhc(cs[r] * TSC);
            _Float16 hh = (_Float16)hv;
            wp[r * 72] = hh;                          // primary (ha rows 0-7 / hb rows 8-15)
            if (isA) wp[r * 72 + 8 * 72] = hh;        // ha dup into rows 8-15
            if (last && !isA) hbF[(q - 2) * 4 + r][jj] = hv;
        }
        __syncthreads();
    };

    // k = 1..256 (k=256 = layer-1-only epilogue step; its ha output is junk-but-finite)
    for (int k = 1; k <= TT; k += 2) {
        step(k,     0, 1, false);
        step(k + 1, 1, 0, (k + 1) == TT);
    }

    // ---- out[m][n] = hbF[m][:] . Wlin[n][:] + blin[n] ----
    int m  = tid >> 5;            // 0..7
    int n0 = (tid & 31) * 2;
    float a0o = blin[n0], a1o = blin[n0 + 1];
    #pragma unroll 8
    for (int j = 0; j < HH; j++) {
        float h = hbF[m][j];
        a0o = fmaf(h, Wlin[(n0 + 0) * HH + j], a0o);
        a1o = fmaf(h, Wlin[(n0 + 1) * HH + j], a1o);
    }
    out[(row0 + m) * HH + n0]     = a0o;
    out[(row0 + m) * HH + n0 + 1] = a1o;
}

extern "C" void kernel_launch(void* const* d_in, const int* in_sizes, int n_in,
                              void* d_out, int out_size, void* d_ws, size_t ws_size,
                              hipStream_t stream) {
    const float* x    = (const float*)d_in[0];
    const float* Wih0 = (const float*)d_in[1];
    const float* Whh0 = (const float*)d_in[2];
    const float* bih0 = (const float*)d_in[3];
    const float* bhh0 = (const float*)d_in[4];
    const float* Wih1 = (const float*)d_in[5];
    const float* Whh1 = (const float*)d_in[6];
    const float* bih1 = (const float*)d_in[7];
    const float* bhh1 = (const float*)d_in[8];
    const float* Wlin = (const float*)d_in[9];
    const float* blin = (const float*)d_in[10];
    // 4096 rows / 8 per block = 512 blocks = 2 blocks/CU
    lstm2_kernel<<<512, 256, 0, stream>>>(x, Wih0, Whh0, bih0, bhh0,
                                          Wih1, Whh1, bih1, bhh1,
                                          Wlin, blin, (float*)d_out);
}

// Round 5
// 411.175 us; speedup vs baseline: 1.2906x; 1.0026x over previous
//
#include <hip/hip_runtime.h>

typedef _Float16 v8h __attribute__((ext_vector_type(8)));
typedef float    v4f __attribute__((ext_vector_type(4)));

#define MFMA16(A,B,C) __builtin_amdgcn_mfma_f32_16x16x32_f16((A),(B),(C),0,0,0)

// Pre-scaled gates (scale folded into W/b):
//   sigmoid gates: y = -log2(e)*z -> sigma = rcp(1 + 2^y)
//   tanh gate:     y = 2*log2(e)*z -> tanh  = 1 - 2*rcp(1 + 2^y)
__device__ __forceinline__ float sigc(float y) {
    return __builtin_amdgcn_rcpf(1.0f + __builtin_exp2f(y));
}
__device__ __forceinline__ float tanhc(float y) {
    return fmaf(-2.0f, __builtin_amdgcn_rcpf(1.0f + __builtin_exp2f(y)), 1.0f);
}

#define RPB 16
#define TT  256
#define HH  64
#define L2E 1.44269504f
#define TSC 2.88539008f   // 2*log2(e)
#define KST 136           // f16 stride per A row: k 0-63 = ha, 64-127 = hb, 8 pad

// 256 blocks x 256 threads = 1 block/CU, 16 rows/block.
// K-concat: A row m = [ha[m] || hb[m]] (K=128). acc0 = ha.Whh0 (chunks 0-1),
// acc1 = ha.Wih1 + hb.Whh1 (chunks 0-3). All 16 C rows useful for BOTH accs ->
// every lane does 8 pointwise instances (4 rows x 2 layers), no selects, no
// dup writes. acc1 bias enters as the C operand of its first MFMA (hoisted
// splat b1v), eliminating in-loop accumulator init movs.
__global__ __launch_bounds__(256, 1)
void lstm2_kernel(const float* __restrict__ x,     // [4096][256]
                  const float* __restrict__ Wih0,  // [256][1]
                  const float* __restrict__ Whh0,  // [256][64]
                  const float* __restrict__ bih0,
                  const float* __restrict__ bhh0,
                  const float* __restrict__ Wih1,  // [256][64]
                  const float* __restrict__ Whh1,  // [256][64]
                  const float* __restrict__ bih1,
                  const float* __restrict__ bhh1,
                  const float* __restrict__ Wlin,  // [64][64]
                  const float* __restrict__ blin,
                  float* __restrict__ out)         // [4096][64]
{
    __shared__ float xl[TT][RPB];                      // 16 KB, x transposed
    __shared__ __align__(16) _Float16 hs[2][RPB][KST]; // 8.5 KB, double-buffered A-tile
    __shared__ float hbF[RPB][HH];                     // 4 KB

    const int tid  = threadIdx.x;
    const int w    = tid >> 6;
    const int l15  = tid & 15;
    const int q    = (tid & 63) >> 4;
    const int row0 = (int)blockIdx.x * RPB;
    const int jj   = w * 16 + l15;

    for (int idx = tid; idx < RPB * TT; idx += 256) {
        int m = idx >> 8, t = idx & (TT - 1);
        xl[t][m] = x[(row0 + m) * TT + t];
    }
    for (int idx = tid; idx < 2 * RPB * KST; idx += 256)
        ((_Float16*)hs)[idx] = (_Float16)0.f;

    // ---- register-stationary, pre-scaled f16 weights ----
    float wi0s[4], b0s[4];
    v4f   b1v[4];                       // splatted layer-1 bias (MFMA C operand)
    v8h wh0[4][2], wi1[4][2], wh1[4][2];
    #pragma unroll
    for (int tau = 0; tau < 4; tau++) {
        float sc = (tau == 2) ? TSC : -L2E;
        int n = tau * 64 + jj;
        wi0s[tau] = Wih0[n] * sc;
        b0s[tau]  = (bih0[n] + bhh0[n]) * sc;
        float b1  = (bih1[n] + bhh1[n]) * sc;
        b1v[tau]  = (v4f){b1, b1, b1, b1};
        #pragma unroll
        for (int kk = 0; kk < 2; kk++) {
            int k0 = kk * 32 + q * 8;   // B-frag: B[k0..k0+7][n=lane&15]
            v8h a, b, c;
            #pragma unroll
            for (int j = 0; j < 8; j++) {
                a[j] = (_Float16)(Whh0[n * HH + k0 + j] * sc);
                b[j] = (_Float16)(Wih1[n * HH + k0 + j] * sc);
                c[j] = (_Float16)(Whh1[n * HH + k0 + j] * sc);
            }
            wh0[tau][kk] = a; wi1[tau][kk] = b; wh1[tau][kk] = c;
        }
    }

    float ca[4] = {0.f, 0.f, 0.f, 0.f};  // layer-0 c for (m=q*4+r, col jj)
    float cb[4] = {0.f, 0.f, 0.f, 0.f};  // layer-1 c for (m=q*4+r, col jj)
    __syncthreads();

    // ---- prologue t=0: ha(0) from x(0) only ----
    #pragma unroll
    for (int r = 0; r < 4; r++) {
        int m = q * 4 + r;
        float xv = xl[0][m];
        float gi = fmaf(xv, wi0s[0], b0s[0]);
        float gf = fmaf(xv, wi0s[1], b0s[1]);
        float gg = fmaf(xv, wi0s[2], b0s[2]);
        float go = fmaf(xv, wi0s[3], b0s[3]);
        float iv = sigc(gi), gv = tanhc(gg), ov = sigc(go);
        (void)gf;
        ca[r] = iv * gv;
        hs[0][m][jj] = (_Float16)(ov * tanhc(ca[r] * TSC));   // ha; hb region stays 0
    }
    __syncthreads();

    // step k: reads buf[p] {ha(k-1), hb(k-2)}, writes buf[pw] {ha(k), hb(k-1)}
    auto step = [&](int k, int p, int pw, bool last) {
        v8h a0 = *(const v8h*)&hs[p][l15][q * 8];          // ha k 0-31
        v8h a1 = *(const v8h*)&hs[p][l15][32 + q * 8];     // ha k 32-63
        v8h b0 = *(const v8h*)&hs[p][l15][64 + q * 8];     // hb k 0-31
        v8h b1 = *(const v8h*)&hs[p][l15][96 + q * 8];     // hb k 32-63
        int kx = (k < TT) ? k : (TT - 1);                  // k=256: junk x, result unused
        v4f xv = *(const v4f*)&xl[kx][q * 4];

        v4f acc0[4], acc1[4];
        #pragma unroll
        for (int tau = 0; tau < 4; tau++) {
            #pragma unroll
            for (int r = 0; r < 4; r++) acc0[tau][r] = fmaf(xv[r], wi0s[tau], b0s[tau]);
            acc1[tau] = MFMA16(a0, wi1[tau][0], b1v[tau]);  // bias as C operand
        }
        #pragma unroll
        for (int tau = 0; tau < 4; tau++) {
            acc0[tau] = MFMA16(a0, wh0[tau][0], acc0[tau]);
            acc0[tau] = MFMA16(a1, wh0[tau][1], acc0[tau]);
            acc1[tau] = MFMA16(a1, wi1[tau][1], acc1[tau]);
            acc1[tau] = MFMA16(b0, wh1[tau][0], acc1[tau]);
            acc1[tau] = MFMA16(b1, wh1[tau][1], acc1[tau]);
        }

        #pragma unroll
        for (int r = 0; r < 4; r++) {
            int m = q * 4 + r;
            {   // layer 0 -> ha(k)
                float iv = sigc(acc0[0][r]), fv = sigc(acc0[1][r]);
                float gv = tanhc(acc0[2][r]), ov = sigc(acc0[3][r]);
                ca[r] = fmaf(fv, ca[r], iv * gv);
                hs[pw][m][jj] = (_Float16)(ov * tanhc(ca[r] * TSC));
            }
            {   // layer 1 -> hb(k-1)
                float iv = sigc(acc1[0][r]), fv = sigc(acc1[1][r]);
                float gv = tanhc(acc1[2][r]), ov = sigc(acc1[3][r]);
                cb[r] = fmaf(fv, cb[r], iv * gv);
                float hv = ov * tanhc(cb[r] * TSC);
                hs[pw][m][64 + jj] = (_Float16)hv;
                if (last) hbF[m][jj] = hv;
            }
        }
        __syncthreads();
    };

    // k = 1..256 (k=256 = layer-1-only epilogue; its ha output is junk-but-finite)
    for (int k = 1; k <= TT; k += 2) {
        step(k,     0, 1, false);
        step(k + 1, 1, 0, (k + 1) == TT);
    }

    // ---- out[m][n] = hbF[m][:] . Wlin[n][:] + blin[n] ----
    int m  = tid >> 4;
    int n0 = (tid & 15) * 4;
    float accO[4] = {blin[n0], blin[n0 + 1], blin[n0 + 2], blin[n0 + 3]};
    #pragma unroll 8
    for (int j = 0; j < HH; j++) {
        float h = hbF[m][j];
        #pragma unroll
        for (int d = 0; d < 4; d++)
            accO[d] = fmaf(h, Wlin[(n0 + d) * HH + j], accO[d]);
    }
    v4f ov = {accO[0], accO[1], accO[2], accO[3]};
    *(v4f*)&out[(row0 + m) * HH + n0] = ov;
}

extern "C" void kernel_launch(void* const* d_in, const int* in_sizes, int n_in,
                              void* d_out, int out_size, void* d_ws, size_t ws_size,
                              hipStream_t stream) {
    const float* x    = (const float*)d_in[0];
    const float* Wih0 = (const float*)d_in[1];
    const float* Whh0 = (const float*)d_in[2];
    const float* bih0 = (const float*)d_in[3];
    const float* bhh0 = (const float*)d_in[4];
    const float* Wih1 = (const float*)d_in[5];
    const float* Whh1 = (const float*)d_in[6];
    const float* bih1 = (const float*)d_in[7];
    const float* bhh1 = (const float*)d_in[8];
    const float* Wlin = (const float*)d_in[9];
    const float* blin = (const float*)d_in[10];
    // 4096 rows / 16 per block = 256 blocks = 1 per CU
    lstm2_kernel<<<256, 256, 0, stream>>>(x, Wih0, Whh0, bih0, bhh0,
                                          Wih1, Whh1, bih1, bhh1,
                                          Wlin, blin, (float*)d_out);
}